// Round 12
// baseline (86.730 us; speedup 1.0000x reference)
//
#include <hip/hip_runtime.h>

#define B_   64
#define N_   2304
#define J_   32
#define L_   16
#define EPS_ 1e-7f
#define NSPL 16      // n-splits
#define NSL  144     // n per split
#define NTHR 256     // 8 n-lanes x 32 j, one batch per block
#define NGRID 1024   // 64 b x 16 sp -> ~4-6 blocks/CU
#define NT   18      // tiles (NSL/8)
#define STR  20      // sred per-slot stride (80 B, 16B-aligned, conflict-avoiding)

// d_ws layout (floats):
//   Ws [N*J*L] | xs_g [B*N] | p0 [B*NSPL*512] | p1 [B*NSPL*512] | p2 [B*NSPL*512] | s0 [B*512]
// All stores exclusive; kernel boundaries are the only synchronization (measured cheapest:
// boundary ~7us << atomic fusion (+25us, R7/R9) << fences (+70us, R6) << grid.sync (R3)).

// ---- prep: Ws = sum_k W; xs_g = sum_i x ----
__global__ __launch_bounds__(256) void prep_kernel(const float* __restrict__ x,
                                                   const float* __restrict__ W,
                                                   float* __restrict__ Ws,
                                                   float* __restrict__ xs_g) {
    const int o = blockIdx.x * 256 + threadIdx.x;
    const int NW4 = N_ * J_ * L_ / 4;               // 294912 float4 outputs
    if (o < NW4) {
        const int n = o >> 7, r = o & 127;          // r = j*4 + l4
        const float4* base = (const float4*)W + (size_t)n * 1024 + (r >> 2) * 32 + (r & 3);
        float4 s = make_float4(0.f, 0.f, 0.f, 0.f);
#pragma unroll
        for (int k = 0; k < 8; ++k) {
            float4 t = base[k * 4];
            s.x += t.x; s.y += t.y; s.z += t.z; s.w += t.w;
        }
        ((float4*)Ws)[o] = s;
    } else {
        const int q = o - NW4;                      // 0 .. B*N-1
        if (q < B_ * N_) {
            const float4* p4 = (const float4*)(x + (size_t)q * 8);
            float4 a = p4[0], c = p4[1];
            xs_g[q] = a.x + a.y + a.z + a.w + c.x + c.y + c.z + c.w;
        }
    }
}

// ---- one routing iteration. Block = (b, sp): 1 batch x 144 n. Grid 1024. ----
// sp is XCD-affine: all 64 b-blocks with the same sp share blk%8 -> one XCD,
// per-XCD Ws footprint 2 slices = 588 KB (L2-resident; measured FETCH -35% in R9).
// 1024 blocks x 256 thr -> ~4-6 co-resident blocks/CU: independent blocks overlap
// each other's prologue/main/tail phases (iters are latency-bound, not BW-bound).
// T=0: uniform weights -> p0. T=1: u = squash(sum p0); sp==0 stores raw s0; -> p1.
// T=2: u = squash(s0) + squash(sum p1); -> p2.
template<int T>
__global__ __launch_bounds__(NTHR) void iter_kernel(const float* __restrict__ Ws,
                                                    const float* __restrict__ xs_g,
                                                    const float* __restrict__ pA,
                                                    float* __restrict__ s0g,
                                                    float* __restrict__ pout) {
    __shared__ float xs_lds[NSL];              // 576 B
    __shared__ float u_lds[544];               // 2.2 KB, [j*17+l] padded (bank-bijective)
    __shared__ float sred[128 * STR];          // 10.2 KB

    const int tid = threadIdx.x;
    const int blk = blockIdx.x;
    const int sp  = ((blk & 7) << 1) | ((blk >> 3) & 1);   // XCD-affine slice
    const int b   = blk >> 4;                  // 0..63
    const int nb  = sp * NSL;

    if (tid < NSL) xs_lds[tid] = xs_g[(size_t)b * N_ + nb + tid];

    const int nl8 = tid >> 5;                  // 0..7 n-lane
    const int j   = tid & 31;                  // capsule
    const float* wbase = Ws + (size_t)nb * 512 + j * 16;

    // pre-issue tiles 0 and 1 (independent of prologue; land during it)
    float4 w0, w1, w2, w3, v0, v1, v2, v3;
    {
        const float4* t0 = (const float4*)(wbase + (size_t)nl8 * 512);
        w0 = t0[0]; w1 = t0[1]; w2 = t0[2]; w3 = t0[3];
        const float4* t1 = (const float4*)(wbase + (size_t)(8 + nl8) * 512);
        v0 = t1[0]; v1 = t1[1]; v2 = t1[2]; v3 = t1[3];
    }

    if constexpr (T == 1) {
        // u = squash(sum of p0 slices); sp==0 blocks also emit the raw sum s0
        for (int q = tid; q < 512; q += NTHR) {
            const float* pp = pA + ((size_t)b * NSPL) * 512 + q;
            float s = 0.f;
#pragma unroll
            for (int i = 0; i < NSPL; ++i) s += pp[i * 512];
            if (sp == 0) s0g[b * 512 + q] = s;
            float sq = s * s;
#pragma unroll
            for (int off = 1; off <= 8; off <<= 1) sq += __shfl_xor(sq, off);
            u_lds[(q >> 4) * 17 + (q & 15)] =
                s * (sq / (1.f + sq) / sqrtf(sq + EPS_));
        }
    } else if constexpr (T == 2) {
        // u = squash(s0) + squash(sum of p1 slices): 17 slice-loads per output
        for (int q = tid; q < 512; q += NTHR) {
            float s = s0g[b * 512 + q];
            float sq = s * s;
#pragma unroll
            for (int off = 1; off <= 8; off <<= 1) sq += __shfl_xor(sq, off);
            float u = s * (sq / (1.f + sq) / sqrtf(sq + EPS_));
            const float* pp = pA + ((size_t)b * NSPL) * 512 + q;
            float s1 = 0.f;
#pragma unroll
            for (int i = 0; i < NSPL; ++i) s1 += pp[i * 512];
            float sq1 = s1 * s1;
#pragma unroll
            for (int off = 1; off <= 8; off <<= 1) sq1 += __shfl_xor(sq1, off);
            u += s1 * (sq1 / (1.f + sq1) / sqrtf(sq1 + EPS_));
            u_lds[(q >> 4) * 17 + (q & 15)] = u;
        }
    }
    __syncthreads();

    float u4[16];
    if constexpr (T > 0) {
#pragma unroll
        for (int l = 0; l < 16; ++l) u4[l] = u_lds[j * 17 + l];
    }

    float acc[16];
#pragma unroll
    for (int l = 0; l < 16; ++l) acc[l] = 0.f;

    // main loop, 2-tile-deep register pipeline: w = tile t, v = tile t+1, n = tile t+2
    for (int tile = 0; tile < NT; ++tile) {
        float4 n0 = make_float4(0.f, 0.f, 0.f, 0.f), n1 = n0, n2 = n0, n3 = n0;
        if (tile + 2 < NT) {
            const float4* nx = (const float4*)(wbase + (size_t)((tile + 2) * 8 + nl8) * 512);
            n0 = nx[0]; n1 = nx[1]; n2 = nx[2]; n3 = nx[3];
        }
        const float xsv = xs_lds[tile * 8 + nl8];
        float wgt;
        if constexpr (T == 0) {
            wgt = xsv * (1.f / 32.f);
        } else {
            float lg = w0.x*u4[0]  + w0.y*u4[1]  + w0.z*u4[2]  + w0.w*u4[3]
                     + w1.x*u4[4]  + w1.y*u4[5]  + w1.z*u4[6]  + w1.w*u4[7]
                     + w2.x*u4[8]  + w2.y*u4[9]  + w2.z*u4[10] + w2.w*u4[11]
                     + w3.x*u4[12] + w3.y*u4[13] + w3.z*u4[14] + w3.w*u4[15];
            lg *= xsv;
            float e = __expf(lg);              // |lg| < ~25: no max-pass needed
            float ss = e;
#pragma unroll
            for (int off = 1; off <= 16; off <<= 1) ss += __shfl_xor(ss, off);
            wgt = (e / ss) * xsv;
        }
        acc[0]  += wgt*w0.x; acc[1]  += wgt*w0.y; acc[2]  += wgt*w0.z; acc[3]  += wgt*w0.w;
        acc[4]  += wgt*w1.x; acc[5]  += wgt*w1.y; acc[6]  += wgt*w1.z; acc[7]  += wgt*w1.w;
        acc[8]  += wgt*w2.x; acc[9]  += wgt*w2.y; acc[10] += wgt*w2.z; acc[11] += wgt*w2.w;
        acc[12] += wgt*w3.x; acc[13] += wgt*w3.y; acc[14] += wgt*w3.z; acc[15] += wgt*w3.w;
        if (tile + 1 < NT) {
            w0 = v0; w1 = v1; w2 = v2; w3 = v3;
            v0 = n0; v1 = n1; v2 = n2; v3 = n3;
        }
    }

    // ---- two-stage n-lane reduction (nl8 4..7 store, nl8 0..3 add) ----
    if (nl8 >= 4) {
        float* sr = sred + (size_t)(tid - 128) * STR;
        ((float4*)sr)[0] = make_float4(acc[0],  acc[1],  acc[2],  acc[3]);
        ((float4*)sr)[1] = make_float4(acc[4],  acc[5],  acc[6],  acc[7]);
        ((float4*)sr)[2] = make_float4(acc[8],  acc[9],  acc[10], acc[11]);
        ((float4*)sr)[3] = make_float4(acc[12], acc[13], acc[14], acc[15]);
    }
    __syncthreads();
    if (nl8 < 4) {
        float* sr = sred + (size_t)tid * STR;
#pragma unroll
        for (int d = 0; d < 4; ++d) {
            float4 t = ((float4*)sr)[d];
            t.x += acc[d*4+0]; t.y += acc[d*4+1]; t.z += acc[d*4+2]; t.w += acc[d*4+3];
            ((float4*)sr)[d] = t;
        }
    }
    __syncthreads();

    // ---- tail: reduce 4 slots, write partial slice (coalesced, exclusive) ----
    for (int q = tid; q < 512; q += NTHR) {
        const int oj = q >> 4, ol = q & 15;
        float s = 0.f;
#pragma unroll
        for (int nl = 0; nl < 4; ++nl)
            s += sred[(size_t)(nl * 32 + oj) * STR + ol];
        pout[((size_t)b * NSPL + sp) * 512 + q] = s;
    }
}

// ---- final squash: out[b][j][l] = squash(sum_sp p2) ----
__global__ __launch_bounds__(512) void final_kernel(const float* __restrict__ p2,
                                                    float* __restrict__ out) {
    const int g = blockIdx.x * 512 + threadIdx.x;   // b*512 + jl
    const int b = g >> 9, jl = g & 511;
    const float* pp = p2 + ((size_t)b * NSPL) * 512 + jl;
    float s = 0.f;
#pragma unroll
    for (int s2 = 0; s2 < NSPL; ++s2) s += pp[s2 * 512];
    float sq = s * s;
#pragma unroll
    for (int off = 1; off <= 8; off <<= 1) sq += __shfl_xor(sq, off);
    out[g] = s * (sq / (1.f + sq) / sqrtf(sq + EPS_));
}

extern "C" void kernel_launch(void* const* d_in, const int* in_sizes, int n_in,
                              void* d_out, int out_size, void* d_ws, size_t ws_size,
                              hipStream_t stream) {
    const float* x = (const float*)d_in[0];   // [B, N, 8]
    const float* W = (const float*)d_in[1];   // [N, J, 8, L]
    float* out = (float*)d_out;               // [B, J, L]

    float* Ws  = (float*)d_ws;                         // N*J*L
    float* xsg = Ws  + (size_t)N_ * J_ * L_;           // B*N
    float* p0  = xsg + (size_t)B_ * N_;                // B*NSPL*512
    float* p1  = p0  + (size_t)B_ * NSPL * 512;        // B*NSPL*512
    float* p2  = p1  + (size_t)B_ * NSPL * 512;        // B*NSPL*512
    float* s0  = p2  + (size_t)B_ * NSPL * 512;        // B*512

    prep_kernel<<<1728, 256, 0, stream>>>(x, W, Ws, xsg);
    iter_kernel<0><<<NGRID, NTHR, 0, stream>>>(Ws, xsg, nullptr, nullptr, p0);
    iter_kernel<1><<<NGRID, NTHR, 0, stream>>>(Ws, xsg, p0, s0, p1);
    iter_kernel<2><<<NGRID, NTHR, 0, stream>>>(Ws, xsg, p1, s0, p2);
    final_kernel<<<64, 512, 0, stream>>>(p2, out);
}

// Round 13
// 75.148 us; speedup vs baseline: 1.1541x; 1.1541x over previous
//
#include <hip/hip_runtime.h>

#define B_   64
#define N_   2304
#define J_   32
#define L_   16
#define EPS_ 1e-7f
#define BG   2       // batches per block (measured optimum: BG=4 -> 76.2, BG=2 -> 75.3, BG=1 -> 86.7)
#define NSPL 16      // n-splits
#define NSL  144     // n per split
#define NTHR 512     // 8 n-lanes x 2 batches x 32 j
#define NGRID 512    // 32 bg x 16 sp -> 2 blocks/CU
#define NT   18      // tiles (NSL/8)
#define STR  20      // sred per-slot stride (80 B, 16B-aligned, conflict-avoiding)

// d_ws layout (floats):
//   Ws [N*J*L] | xs_g [B*N] | p0 [B*NSPL*512] | p1 [B*NSPL*512] | p2 [B*NSPL*512] | s0 [B*512]
// All stores exclusive; kernel boundaries are the only synchronization (measured cheapest:
// boundary ~7us << atomic fusion (+25us, R7/R9) << fences (+70us, R6) << grid.sync (R3)).

// ---- prep: Ws = sum_k W; xs_g = sum_i x ----
__global__ __launch_bounds__(256) void prep_kernel(const float* __restrict__ x,
                                                   const float* __restrict__ W,
                                                   float* __restrict__ Ws,
                                                   float* __restrict__ xs_g) {
    const int o = blockIdx.x * 256 + threadIdx.x;
    const int NW4 = N_ * J_ * L_ / 4;               // 294912 float4 outputs
    if (o < NW4) {
        const int n = o >> 7, r = o & 127;          // r = j*4 + l4
        const float4* base = (const float4*)W + (size_t)n * 1024 + (r >> 2) * 32 + (r & 3);
        float4 s = make_float4(0.f, 0.f, 0.f, 0.f);
#pragma unroll
        for (int k = 0; k < 8; ++k) {
            float4 t = base[k * 4];
            s.x += t.x; s.y += t.y; s.z += t.z; s.w += t.w;
        }
        ((float4*)Ws)[o] = s;
    } else {
        const int q = o - NW4;                      // 0 .. B*N-1
        if (q < B_ * N_) {
            const float4* p4 = (const float4*)(x + (size_t)q * 8);
            float4 a = p4[0], c = p4[1];
            xs_g[q] = a.x + a.y + a.z + a.w + c.x + c.y + c.z + c.w;
        }
    }
}

// ---- one routing iteration. Block = (bg, sp): 2 batches x 144 n. Grid 512. ----
// sp is XCD-affine: all 32 bg-blocks with the same sp share blk%8 -> one XCD,
// per-XCD Ws footprint 2 slices = 588 KB (L2-resident; measured FETCH -35% in R9).
// Within a wave the two b4 lanes read identical Ws addresses (hardware-merged),
// so Ws L2 traffic is halved vs BG=1 (R12's regression isolated this term).
// T=0: uniform weights -> p0. T=1: u = squash(sum p0); sp==0 stores raw s0; -> p1.
// T=2: u = squash(s0) + squash(sum p1); -> p2.
template<int T>
__global__ __launch_bounds__(NTHR) void iter_kernel(const float* __restrict__ Ws,
                                                    const float* __restrict__ xs_g,
                                                    const float* __restrict__ pA,
                                                    float* __restrict__ s0g,
                                                    float* __restrict__ pout) {
    __shared__ float xs_lds[BG * NSL];         // 1.2 KB
    __shared__ float u_lds[BG * 544];          // 4.4 KB, [b][j*17+l] padded (bank-bijective)
    __shared__ float sred[256 * STR];          // 20.5 KB

    const int tid = threadIdx.x;
    const int blk = blockIdx.x;
    const int sp  = ((blk & 7) << 1) | ((blk >> 3) & 1);   // XCD-affine slice
    const int bg  = blk >> 4;                  // 0..31
    const int bb  = bg * BG;
    const int nb  = sp * NSL;

    if (tid < BG * NSL) {
        const int b4f = tid / NSL, nlf = tid - b4f * NSL;
        xs_lds[tid] = xs_g[(size_t)(bb + b4f) * N_ + nb + nlf];
    }

    const int nl8 = tid >> 6;                  // 0..7 n-lane
    const int b4  = (tid >> 5) & 1;            // batch within group
    const int j   = tid & 31;                  // capsule
    const float* wbase = Ws + (size_t)nb * 512 + j * 16;

    // pre-issue tile-0 Ws loads (independent of prologue; lands during it)
    const float4* wr0 = (const float4*)(wbase + (size_t)nl8 * 512);
    float4 w0 = wr0[0], w1 = wr0[1], w2 = wr0[2], w3 = wr0[3];

    if constexpr (T == 1) {
        // u = squash(sum of p0 slices); sp==0 blocks also emit the raw sum s0
        for (int q = tid; q < BG * 512; q += NTHR) {
            const int ob = q >> 9, jl = q & 511;
            const float* pp = pA + ((size_t)(bb + ob) * NSPL) * 512 + jl;
            float s = 0.f;
#pragma unroll
            for (int i = 0; i < NSPL; ++i) s += pp[i * 512];
            if (sp == 0) s0g[(bb + ob) * 512 + jl] = s;
            float sq = s * s;
#pragma unroll
            for (int off = 1; off <= 8; off <<= 1) sq += __shfl_xor(sq, off);
            u_lds[ob * 544 + (jl >> 4) * 17 + (jl & 15)] =
                s * (sq / (1.f + sq) / sqrtf(sq + EPS_));
        }
    } else if constexpr (T == 2) {
        // u = squash(s0) + squash(sum of p1 slices): 17 slice-loads instead of 32
        for (int q = tid; q < BG * 512; q += NTHR) {
            const int ob = q >> 9, jl = q & 511;
            float s = s0g[(bb + ob) * 512 + jl];
            float sq = s * s;
#pragma unroll
            for (int off = 1; off <= 8; off <<= 1) sq += __shfl_xor(sq, off);
            float u = s * (sq / (1.f + sq) / sqrtf(sq + EPS_));
            const float* pp = pA + ((size_t)(bb + ob) * NSPL) * 512 + jl;
            float s1 = 0.f;
#pragma unroll
            for (int i = 0; i < NSPL; ++i) s1 += pp[i * 512];
            float sq1 = s1 * s1;
#pragma unroll
            for (int off = 1; off <= 8; off <<= 1) sq1 += __shfl_xor(sq1, off);
            u += s1 * (sq1 / (1.f + sq1) / sqrtf(sq1 + EPS_));
            u_lds[ob * 544 + (jl >> 4) * 17 + (jl & 15)] = u;
        }
    }
    __syncthreads();

    float u4[16];
    if constexpr (T > 0) {
#pragma unroll
        for (int l = 0; l < 16; ++l) u4[l] = u_lds[b4 * 544 + j * 17 + l];
    }

    float acc[16];
#pragma unroll
    for (int l = 0; l < 16; ++l) acc[l] = 0.f;

    const float* xbase = xs_lds + b4 * NSL;

    for (int tile = 0; tile < NT; ++tile) {
        // prefetch next tile's Ws row before consuming this one
        float4 n0, n1, n2, n3;
        if (tile + 1 < NT) {
            const float4* nx = (const float4*)(wbase + (size_t)((tile + 1) * 8 + nl8) * 512);
            n0 = nx[0]; n1 = nx[1]; n2 = nx[2]; n3 = nx[3];
        }
        const float xsv = xbase[tile * 8 + nl8];
        float wgt;
        if constexpr (T == 0) {
            wgt = xsv * (1.f / 32.f);
        } else {
            float lg = w0.x*u4[0]  + w0.y*u4[1]  + w0.z*u4[2]  + w0.w*u4[3]
                     + w1.x*u4[4]  + w1.y*u4[5]  + w1.z*u4[6]  + w1.w*u4[7]
                     + w2.x*u4[8]  + w2.y*u4[9]  + w2.z*u4[10] + w2.w*u4[11]
                     + w3.x*u4[12] + w3.y*u4[13] + w3.z*u4[14] + w3.w*u4[15];
            lg *= xsv;
            float e = __expf(lg);              // |lg| < ~25: no max-pass needed
            float ss = e;
#pragma unroll
            for (int off = 1; off <= 16; off <<= 1) ss += __shfl_xor(ss, off);
            wgt = (e / ss) * xsv;
        }
        acc[0]  += wgt*w0.x; acc[1]  += wgt*w0.y; acc[2]  += wgt*w0.z; acc[3]  += wgt*w0.w;
        acc[4]  += wgt*w1.x; acc[5]  += wgt*w1.y; acc[6]  += wgt*w1.z; acc[7]  += wgt*w1.w;
        acc[8]  += wgt*w2.x; acc[9]  += wgt*w2.y; acc[10] += wgt*w2.z; acc[11] += wgt*w2.w;
        acc[12] += wgt*w3.x; acc[13] += wgt*w3.y; acc[14] += wgt*w3.z; acc[15] += wgt*w3.w;
        if (tile + 1 < NT) { w0 = n0; w1 = n1; w2 = n2; w3 = n3; }
    }

    // ---- two-stage n-lane reduction (nl8 4..7 store, nl8 0..3 add) ----
    if (nl8 >= 4) {
        float* sr = sred + (size_t)(tid - 256) * STR;
        ((float4*)sr)[0] = make_float4(acc[0],  acc[1],  acc[2],  acc[3]);
        ((float4*)sr)[1] = make_float4(acc[4],  acc[5],  acc[6],  acc[7]);
        ((float4*)sr)[2] = make_float4(acc[8],  acc[9],  acc[10], acc[11]);
        ((float4*)sr)[3] = make_float4(acc[12], acc[13], acc[14], acc[15]);
    }
    __syncthreads();
    if (nl8 < 4) {
        float* sr = sred + (size_t)tid * STR;
#pragma unroll
        for (int d = 0; d < 4; ++d) {
            float4 t = ((float4*)sr)[d];
            t.x += acc[d*4+0]; t.y += acc[d*4+1]; t.z += acc[d*4+2]; t.w += acc[d*4+3];
            ((float4*)sr)[d] = t;
        }
    }
    __syncthreads();

    // ---- tail: reduce 4 slots, write partial slice (coalesced, exclusive) ----
    for (int q = tid; q < BG * 512; q += NTHR) {
        const int ob = q >> 9, jl = q & 511;
        const int oj = jl >> 4, ol = jl & 15;
        float s = 0.f;
#pragma unroll
        for (int nl = 0; nl < 4; ++nl)
            s += sred[(size_t)(nl * 64 + ob * 32 + oj) * STR + ol];
        pout[((size_t)(bb + ob) * NSPL + sp) * 512 + jl] = s;
    }
}

// ---- final squash: out[b][j][l] = squash(sum_sp p2) ----
__global__ __launch_bounds__(512) void final_kernel(const float* __restrict__ p2,
                                                    float* __restrict__ out) {
    const int g = blockIdx.x * 512 + threadIdx.x;   // b*512 + jl
    const int b = g >> 9, jl = g & 511;
    const float* pp = p2 + ((size_t)b * NSPL) * 512 + jl;
    float s = 0.f;
#pragma unroll
    for (int s2 = 0; s2 < NSPL; ++s2) s += pp[s2 * 512];
    float sq = s * s;
#pragma unroll
    for (int off = 1; off <= 8; off <<= 1) sq += __shfl_xor(sq, off);
    out[g] = s * (sq / (1.f + sq) / sqrtf(sq + EPS_));
}

extern "C" void kernel_launch(void* const* d_in, const int* in_sizes, int n_in,
                              void* d_out, int out_size, void* d_ws, size_t ws_size,
                              hipStream_t stream) {
    const float* x = (const float*)d_in[0];   // [B, N, 8]
    const float* W = (const float*)d_in[1];   // [N, J, 8, L]
    float* out = (float*)d_out;               // [B, J, L]

    float* Ws  = (float*)d_ws;                         // N*J*L
    float* xsg = Ws  + (size_t)N_ * J_ * L_;           // B*N
    float* p0  = xsg + (size_t)B_ * N_;                // B*NSPL*512
    float* p1  = p0  + (size_t)B_ * NSPL * 512;        // B*NSPL*512
    float* p2  = p1  + (size_t)B_ * NSPL * 512;        // B*NSPL*512
    float* s0  = p2  + (size_t)B_ * NSPL * 512;        // B*512

    prep_kernel<<<1728, 256, 0, stream>>>(x, W, Ws, xsg);
    iter_kernel<0><<<NGRID, NTHR, 0, stream>>>(Ws, xsg, nullptr, nullptr, p0);
    iter_kernel<1><<<NGRID, NTHR, 0, stream>>>(Ws, xsg, p0, s0, p1);
    iter_kernel<2><<<NGRID, NTHR, 0, stream>>>(Ws, xsg, p1, s0, p2);
    final_kernel<<<64, 512, 0, stream>>>(p2, out);
}